// Round 3
// baseline (505.282 us; speedup 1.0000x reference)
//
#include <hip/hip_runtime.h>

#define D_MODEL 1024
#define NH 16
#define HD 64
#define KRET 32
#define BANK 131072
#define BB 8
#define TT 2048
#define MTOK 16384
#define EPSN 1e-12f

typedef __attribute__((ext_vector_type(8))) short bf16x8;
typedef __attribute__((ext_vector_type(8))) unsigned short u16x8;
typedef __attribute__((ext_vector_type(4))) float f32x4;

__device__ __forceinline__ unsigned short f2bf(float f) {
  unsigned int u = __float_as_uint(f);
  u += 0x7fffu + ((u >> 16) & 1u);
  return (unsigned short)(u >> 16);
}
__device__ __forceinline__ float bf2f(unsigned short h) {
  return __uint_as_float(((unsigned int)h) << 16);
}

__device__ __forceinline__ void gload16(const void* g, void* l) {
  __builtin_amdgcn_global_load_lds(
      (const __attribute__((address_space(1))) unsigned int*)g,
      (__attribute__((address_space(3))) unsigned int*)l, 16, 0, 0);
}

// ---------------- fused: x -> bf16 AND per-(b,chunk32) partial sums ----------------
__global__ __launch_bounds__(256) void k_conv_mean(const float* __restrict__ x,
                                                   unsigned short* __restrict__ xb,
                                                   float* __restrict__ part) {
  int ch = blockIdx.x, b = blockIdx.y, tid = threadIdx.x;
  const float4* xp = (const float4*)(x + ((size_t)b * TT + ch * 32) * D_MODEL);
  ushort4* xo = (ushort4*)(xb + ((size_t)b * TT + ch * 32) * D_MODEL);
  float4 acc = {0.f, 0.f, 0.f, 0.f};
#pragma unroll 4
  for (int t = 0; t < 32; t++) {
    float4 v = xp[t * 256 + tid];
    acc.x += v.x; acc.y += v.y; acc.z += v.z; acc.w += v.w;
    ushort4 o;
    o.x = f2bf(v.x); o.y = f2bf(v.y); o.z = f2bf(v.z); o.w = f2bf(v.w);
    xo[t * 256 + tid] = o;
  }
  ((float4*)part)[((size_t)b * 64 + ch) * 256 + tid] = acc;
}

// ---------------- weight transpose + bf16: WT[n][k] = bf16(W[k][n]) ----------------
__global__ __launch_bounds__(256) void k_transW(const float* W0, const float* W1,
                                                const float* W2, const float* W3,
                                                unsigned short* T0, unsigned short* T1,
                                                unsigned short* T2, unsigned short* T3) {
  const float* W; unsigned short* T;
  switch (blockIdx.z) {
    case 0: W = W0; T = T0; break;
    case 1: W = W1; T = T1; break;
    case 2: W = W2; T = T2; break;
    default: W = W3; T = T3; break;
  }
  __shared__ float tile[64][65];
  int k0 = blockIdx.y * 64, n0 = blockIdx.x * 64;
  int tid = threadIdx.x;
#pragma unroll
  for (int i = 0; i < 16; i++) {
    int idx = tid + i * 256; int r = idx >> 6, c = idx & 63;
    tile[r][c] = W[(size_t)(k0 + r) * D_MODEL + n0 + c];
  }
  __syncthreads();
#pragma unroll
  for (int i = 0; i < 16; i++) {
    int idx = tid + i * 256; int r = idx >> 6, c = idx & 63;
    T[(size_t)(n0 + r) * D_MODEL + k0 + c] = f2bf(tile[c][r]);
  }
}

// ---------------- finish mean (64 partials) + normalize q ----------------
__global__ __launch_bounds__(256) void k_qnorm(const float* __restrict__ part,
                                               float* __restrict__ qn) {
  int b = blockIdx.x; int tid = threadIdx.x;
  __shared__ float red[4];
  const float4* pp = (const float4*)part + (size_t)b * 64 * 256 + tid;
  float4 a = {0.f, 0.f, 0.f, 0.f};
#pragma unroll 8
  for (int p = 0; p < 64; p++) {
    float4 v = pp[(size_t)p * 256];
    a.x += v.x; a.y += v.y; a.z += v.z; a.w += v.w;
  }
  const float sc = 1.f / (float)TT;
  a.x *= sc; a.y *= sc; a.z *= sc; a.w *= sc;
  float ss = a.x * a.x + a.y * a.y + a.z * a.z + a.w * a.w;
#pragma unroll
  for (int m = 32; m >= 1; m >>= 1) ss += __shfl_xor(ss, m);
  if ((tid & 63) == 0) red[tid >> 6] = ss;
  __syncthreads();
  float tot = red[0] + red[1] + red[2] + red[3];
  float inv = 1.f / fmaxf(sqrtf(tot), EPSN);
  float4 o = {a.x * inv, a.y * inv, a.z * inv, a.w * inv};
  ((float4*)qn)[(size_t)b * 256 + tid] = o;
}

// ---------------- cosine sims: one wave per 4 key rows ----------------
__global__ __launch_bounds__(256) void k_sims(const float* __restrict__ mk,
                                              const float* __restrict__ qn,
                                              float* __restrict__ sims) {
  int wave = threadIdx.x >> 6, lane = threadIdx.x & 63;
  int row0 = (blockIdx.x * 4 + wave) * 4;
  float4 kv[4][4];
#pragma unroll
  for (int r = 0; r < 4; r++) {
    const float4* kr = (const float4*)(mk + (size_t)(row0 + r) * D_MODEL);
#pragma unroll
    for (int i = 0; i < 4; i++) kv[r][i] = kr[lane + 64 * i];
  }
  float ss[4] = {0.f, 0.f, 0.f, 0.f};
#pragma unroll
  for (int r = 0; r < 4; r++)
#pragma unroll
    for (int i = 0; i < 4; i++)
      ss[r] += kv[r][i].x * kv[r][i].x + kv[r][i].y * kv[r][i].y +
               kv[r][i].z * kv[r][i].z + kv[r][i].w * kv[r][i].w;
  float dots[8][4];
#pragma unroll
  for (int b = 0; b < 8; b++)
#pragma unroll
    for (int r = 0; r < 4; r++) dots[b][r] = 0.f;
#pragma unroll
  for (int b = 0; b < 8; b++) {
    const float4* qb = (const float4*)(qn + (size_t)b * D_MODEL);
#pragma unroll
    for (int i = 0; i < 4; i++) {
      float4 q4 = qb[lane + 64 * i];
#pragma unroll
      for (int r = 0; r < 4; r++)
        dots[b][r] += kv[r][i].x * q4.x + kv[r][i].y * q4.y +
                      kv[r][i].z * q4.z + kv[r][i].w * q4.w;
    }
  }
#pragma unroll
  for (int m = 32; m >= 1; m >>= 1) {
#pragma unroll
    for (int r = 0; r < 4; r++) ss[r] += __shfl_xor(ss[r], m);
#pragma unroll
    for (int b = 0; b < 8; b++)
#pragma unroll
      for (int r = 0; r < 4; r++) dots[b][r] += __shfl_xor(dots[b][r], m);
  }
  if (lane == 0) {
#pragma unroll
    for (int r = 0; r < 4; r++) {
      float inv = 1.f / fmaxf(sqrtf(ss[r]), EPSN);
#pragma unroll
      for (int b = 0; b < 8; b++)
        sims[(size_t)b * BANK + row0 + r] = dots[b][r] * inv;
    }
  }
}

// ---------------- two-stage exact top-32 ----------------
__global__ __launch_bounds__(256) void k_topk_local(const float* __restrict__ sims,
                                                    float* __restrict__ cval,
                                                    int* __restrict__ cidx) {
  int b = blockIdx.y, chunk = blockIdx.x;
  int tid = threadIdx.x, wave = tid >> 6, lane = tid & 63;
  const float* sb = sims + (size_t)b * BANK + chunk * 2048;
  float v[8]; int gi[8];
#pragma unroll
  for (int j = 0; j < 8; j++) {
    int loc = j * 256 + tid;
    v[j] = sb[loc];
    gi[j] = chunk * 2048 + loc;
  }
  __shared__ float wv[4]; __shared__ int wi[4];
  __shared__ int bcast;
  for (int it = 0; it < KRET; ++it) {
    float best = -1e30f; int besti = 1 << 30;
#pragma unroll
    for (int j = 0; j < 8; j++)
      if (v[j] > best || (v[j] == best && gi[j] < besti)) { best = v[j]; besti = gi[j]; }
#pragma unroll
    for (int m = 32; m >= 1; m >>= 1) {
      float ov = __shfl_xor(best, m); int oi = __shfl_xor(besti, m);
      if (ov > best || (ov == best && oi < besti)) { best = ov; besti = oi; }
    }
    if (lane == 0) { wv[wave] = best; wi[wave] = besti; }
    __syncthreads();
    if (tid == 0) {
      float fb = wv[0]; int fi = wi[0];
      for (int w = 1; w < 4; w++)
        if (wv[w] > fb || (wv[w] == fb && wi[w] < fi)) { fb = wv[w]; fi = wi[w]; }
      bcast = fi;
      cval[((size_t)b * 64 + chunk) * KRET + it] = fb;
      cidx[((size_t)b * 64 + chunk) * KRET + it] = fi;
    }
    __syncthreads();
    int w = bcast;
#pragma unroll
    for (int j = 0; j < 8; j++)
      if (gi[j] == w) v[j] = -1e30f;
  }
}

__global__ __launch_bounds__(256) void k_topk_merge(const float* __restrict__ cval,
                                                    const int* __restrict__ cidx,
                                                    int* __restrict__ idx) {
  int b = blockIdx.x;
  int tid = threadIdx.x, wave = tid >> 6, lane = tid & 63;
  const float* cv = cval + (size_t)b * 2048;
  const int* ci = cidx + (size_t)b * 2048;
  float v[8]; int gi[8];
#pragma unroll
  for (int j = 0; j < 8; j++) {
    int loc = j * 256 + tid;
    v[j] = cv[loc];
    gi[j] = ci[loc];
  }
  __shared__ float wv[4]; __shared__ int wi[4];
  __shared__ int bcast;
  for (int it = 0; it < KRET; ++it) {
    float best = -1e30f; int besti = 1 << 30;
#pragma unroll
    for (int j = 0; j < 8; j++)
      if (v[j] > best || (v[j] == best && gi[j] < besti)) { best = v[j]; besti = gi[j]; }
#pragma unroll
    for (int m = 32; m >= 1; m >>= 1) {
      float ov = __shfl_xor(best, m); int oi = __shfl_xor(besti, m);
      if (ov > best || (ov == best && oi < besti)) { best = ov; besti = oi; }
    }
    if (lane == 0) { wv[wave] = best; wi[wave] = besti; }
    __syncthreads();
    if (tid == 0) {
      float fb = wv[0]; int fi = wi[0];
      for (int w = 1; w < 4; w++)
        if (wv[w] > fb || (wv[w] == fb && wi[w] < fi)) { fb = wv[w]; fi = wi[w]; }
      bcast = fi;
      idx[b * KRET + it] = fi;
    }
    __syncthreads();
    int w = bcast;
#pragma unroll
    for (int j = 0; j < 8; j++)
      if (gi[j] == w) v[j] = -1e30f;
  }
}

// ---------------- KV projection with fused gather: A rows = mv[idx[.]] ----------------
// C = gathered(256x1024) @ [Wk;Wv]^T (2048x1024) -> K,V f32 (B,H,KRET,HD)
__global__ __launch_bounds__(256) void k_kvgemm(const float* __restrict__ mv,
                                                const int* __restrict__ idx_g,
                                                const unsigned short* __restrict__ Bt,
                                                float* __restrict__ Kout,
                                                float* __restrict__ Vout) {
  __shared__ __align__(16) unsigned short As[128 * 32];
  __shared__ __align__(16) unsigned short Bs[128 * 32];
  __shared__ int idxs[128];
  const int tid = threadIdx.x;
  const int wave = tid >> 6, lane = tid & 63;
  const int bm = blockIdx.x * 128, bn = blockIdx.y * 128;
  const int wm = (wave >> 1) * 64, wn = (wave & 1) * 64;
  const int frow = lane & 15, kg = lane >> 4;
  const int K = 1024;

  if (tid < 128) idxs[tid] = idx_g[bm + tid];
  __syncthreads();

  f32x4 acc[4][4] = {};

  const int row0 = tid >> 2, col0 = (tid & 3) * 8;
  const int row1 = row0 + 64;
  const int g0 = tid * 8;
  const int g1 = 2048 + tid * 8;
  const unsigned short* b0 = Bt + (size_t)(bn + (g0 >> 5)) * K + (g0 & 31);
  const unsigned short* b1 = Bt + (size_t)(bn + (g1 >> 5)) * K + (g1 & 31);
  unsigned short* lB0 = &Bs[wave * 512];
  unsigned short* lB1 = &Bs[2048 + wave * 512];
  const float* src0 = mv + (size_t)idxs[row0] * D_MODEL + col0;
  const float* src1 = mv + (size_t)idxs[row1] * D_MODEL + col0;

  for (int k0 = 0; k0 < K; k0 += 32) {
    gload16(b0 + k0, lB0);
    gload16(b1 + k0, lB1);
    float4 u0 = *(const float4*)(src0 + k0);
    float4 w0 = *(const float4*)(src0 + k0 + 4);
    float4 u1 = *(const float4*)(src1 + k0);
    float4 w1 = *(const float4*)(src1 + k0 + 4);
    u16x8 p0, p1;
    p0[0] = f2bf(u0.x); p0[1] = f2bf(u0.y); p0[2] = f2bf(u0.z); p0[3] = f2bf(u0.w);
    p0[4] = f2bf(w0.x); p0[5] = f2bf(w0.y); p0[6] = f2bf(w0.z); p0[7] = f2bf(w0.w);
    p1[0] = f2bf(u1.x); p1[1] = f2bf(u1.y); p1[2] = f2bf(u1.z); p1[3] = f2bf(u1.w);
    p1[4] = f2bf(w1.x); p1[5] = f2bf(w1.y); p1[6] = f2bf(w1.z); p1[7] = f2bf(w1.w);
    *(u16x8*)&As[row0 * 32 + col0] = p0;
    *(u16x8*)&As[row1 * 32 + col0] = p1;
    __syncthreads();
    bf16x8 fa[4], fb[4];
#pragma unroll
    for (int i = 0; i < 4; i++)
      fa[i] = *(const bf16x8*)&As[(wm + i * 16 + frow) * 32 + kg * 8];
#pragma unroll
    for (int i = 0; i < 4; i++)
      fb[i] = *(const bf16x8*)&Bs[(wn + i * 16 + frow) * 32 + kg * 8];
#pragma unroll
    for (int i = 0; i < 4; i++)
#pragma unroll
      for (int j = 0; j < 4; j++)
        acc[i][j] = __builtin_amdgcn_mfma_f32_16x16x32_bf16(fa[i], fb[j], acc[i][j], 0, 0, 0);
    __syncthreads();
  }

  const int crow = (lane >> 4) * 4, ccol = lane & 15;
#pragma unroll
  for (int i = 0; i < 4; i++)
#pragma unroll
    for (int j = 0; j < 4; j++)
#pragma unroll
      for (int r = 0; r < 4; r++) {
        int gm = bm + wm + i * 16 + crow + r;
        int gn = bn + wn + j * 16 + ccol;
        int b = gm >> 5, jj = gm & 31;
        if (gn < 1024) {
          int h = gn >> 6, d = gn & 63;
          Kout[((((size_t)b * NH + h) * KRET + jj) << 6) + d] = acc[i][j][r];
        } else {
          int gn2 = gn - 1024;
          int h = gn2 >> 6, d = gn2 & 63;
          Vout[((((size_t)b * NH + h) * KRET + jj) << 6) + d] = acc[i][j][r];
        }
      }
}

// ---------------- bf16 MFMA GEMM, 128x128 tile, BK=32 (m97 structure) ----------------
// MODE 0: Q-proj -> out_b bf16 in (B,H,T,hd)
// MODE 2: O-proj -> out_f = xres + gate * acc (f32)
template <int MODE>
__global__ __launch_bounds__(256) void k_gemm(const unsigned short* __restrict__ A,
                                              const unsigned short* __restrict__ Bt,
                                              float* __restrict__ out_f,
                                              unsigned short* __restrict__ out_b,
                                              const float* __restrict__ xres,
                                              const float* __restrict__ gatep) {
  __shared__ __align__(16) unsigned short As[128 * 32];
  __shared__ __align__(16) unsigned short Bs[128 * 32];
  const int tid = threadIdx.x;
  const int wave = tid >> 6, lane = tid & 63;
  const int bm = blockIdx.x * 128, bn = blockIdx.y * 128;
  const int wm = (wave >> 1) * 64, wn = (wave & 1) * 64;
  const int frow = lane & 15, kg = lane >> 4;
  const int K = 1024;

  f32x4 acc[4][4] = {};

  const int g0 = tid * 8;
  const int g1 = 2048 + tid * 8;
  const unsigned short* a0 = A + (size_t)(bm + (g0 >> 5)) * K + (g0 & 31);
  const unsigned short* a1 = A + (size_t)(bm + (g1 >> 5)) * K + (g1 & 31);
  const unsigned short* b0 = Bt + (size_t)(bn + (g0 >> 5)) * K + (g0 & 31);
  const unsigned short* b1 = Bt + (size_t)(bn + (g1 >> 5)) * K + (g1 & 31);
  unsigned short* lA0 = &As[wave * 512];
  unsigned short* lA1 = &As[2048 + wave * 512];
  unsigned short* lB0 = &Bs[wave * 512];
  unsigned short* lB1 = &Bs[2048 + wave * 512];

  for (int k0 = 0; k0 < K; k0 += 32) {
    gload16(a0 + k0, lA0);
    gload16(a1 + k0, lA1);
    gload16(b0 + k0, lB0);
    gload16(b1 + k0, lB1);
    __syncthreads();
    bf16x8 fa[4], fb[4];
#pragma unroll
    for (int i = 0; i < 4; i++)
      fa[i] = *(const bf16x8*)&As[(wm + i * 16 + frow) * 32 + kg * 8];
#pragma unroll
    for (int i = 0; i < 4; i++)
      fb[i] = *(const bf16x8*)&Bs[(wn + i * 16 + frow) * 32 + kg * 8];
#pragma unroll
    for (int i = 0; i < 4; i++)
#pragma unroll
      for (int j = 0; j < 4; j++)
        acc[i][j] = __builtin_amdgcn_mfma_f32_16x16x32_bf16(fa[i], fb[j], acc[i][j], 0, 0, 0);
    __syncthreads();
  }

  const int crow = (lane >> 4) * 4, ccol = lane & 15;
  if (MODE == 2) {
    float gate = 1.f / (1.f + __expf(-gatep[0]));
#pragma unroll
    for (int i = 0; i < 4; i++)
#pragma unroll
      for (int j = 0; j < 4; j++)
#pragma unroll
        for (int r = 0; r < 4; r++) {
          int gm = bm + wm + i * 16 + crow + r;
          int gn = bn + wn + j * 16 + ccol;
          size_t off = (size_t)gm * D_MODEL + gn;
          out_f[off] = xres[off] + gate * acc[i][j][r];
        }
  } else {
#pragma unroll
    for (int i = 0; i < 4; i++)
#pragma unroll
      for (int j = 0; j < 4; j++)
#pragma unroll
        for (int r = 0; r < 4; r++) {
          int gm = bm + wm + i * 16 + crow + r;
          int gn = bn + wn + j * 16 + ccol;
          int b = gm >> 11, t = gm & 2047, h = gn >> 6, d = gn & 63;
          out_b[((((size_t)b * NH + h) * TT + t) << 6) + d] = f2bf(acc[i][j][r]);
        }
  }
}

// ---------------- cross-attention over k=32 retrieved docs ----------------
__global__ __launch_bounds__(256) void k_attn(const unsigned short* __restrict__ Qb,
                                              const float* __restrict__ Kws,
                                              const float* __restrict__ Vws,
                                              unsigned short* __restrict__ ctx) {
  __shared__ __align__(16) float Ks[KRET * HD];
  __shared__ __align__(16) float Vs[KRET * HD];
  int bh = blockIdx.y; int b = bh >> 4, h = bh & 15;
  int tid = threadIdx.x;
  int t = blockIdx.x * 256 + tid;
  const float4* kp = (const float4*)(Kws + (size_t)bh * KRET * HD);
  const float4* vp = (const float4*)(Vws + (size_t)bh * KRET * HD);
  ((float4*)Ks)[tid] = kp[tid];
  ((float4*)Ks)[tid + 256] = kp[tid + 256];
  ((float4*)Vs)[tid] = vp[tid];
  ((float4*)Vs)[tid + 256] = vp[tid + 256];
  __syncthreads();

  const uint4* qp = (const uint4*)(Qb + ((size_t)bh * TT + t) * HD);
  float q[64];
#pragma unroll
  for (int i = 0; i < 8; i++) {
    uint4 u = qp[i];
    unsigned vals[4] = {u.x, u.y, u.z, u.w};
#pragma unroll
    for (int w = 0; w < 4; w++) {
      q[i * 8 + w * 2 + 0] = bf2f((unsigned short)(vals[w] & 0xffffu));
      q[i * 8 + w * 2 + 1] = bf2f((unsigned short)(vals[w] >> 16));
    }
  }
  float s[KRET];
#pragma unroll
  for (int j = 0; j < KRET; j++) {
    const float4* kr = (const float4*)&Ks[j * HD];
    float a = 0.f;
#pragma unroll
    for (int d4 = 0; d4 < 16; d4++) {
      float4 kk = kr[d4];
      a += q[d4 * 4 + 0] * kk.x + q[d4 * 4 + 1] * kk.y +
           q[d4 * 4 + 2] * kk.z + q[d4 * 4 + 3] * kk.w;
    }
    s[j] = a * 0.125f;
  }
  float m = s[0];
#pragma unroll
  for (int j = 1; j < KRET; j++) m = fmaxf(m, s[j]);
  float sum = 0.f;
#pragma unroll
  for (int j = 0; j < KRET; j++) { s[j] = __expf(s[j] - m); sum += s[j]; }
  float inv = 1.f / sum;
  float o[64];
#pragma unroll
  for (int d = 0; d < 64; d++) o[d] = 0.f;
#pragma unroll
  for (int j = 0; j < KRET; j++) {
    float p = s[j] * inv;
    const float4* vr = (const float4*)&Vs[j * HD];
#pragma unroll
    for (int d4 = 0; d4 < 16; d4++) {
      float4 vv = vr[d4];
      o[d4 * 4 + 0] += p * vv.x; o[d4 * 4 + 1] += p * vv.y;
      o[d4 * 4 + 2] += p * vv.z; o[d4 * 4 + 3] += p * vv.w;
    }
  }
  unsigned short* cp = ctx + ((size_t)(b * TT + t)) * D_MODEL + h * HD;
#pragma unroll
  for (int d4 = 0; d4 < 16; d4++) {
    ushort4 w4;
    w4.x = f2bf(o[d4 * 4 + 0]); w4.y = f2bf(o[d4 * 4 + 1]);
    w4.z = f2bf(o[d4 * 4 + 2]); w4.w = f2bf(o[d4 * 4 + 3]);
    ((ushort4*)cp)[d4] = w4;
  }
}

extern "C" void kernel_launch(void* const* d_in, const int* in_sizes, int n_in,
                              void* d_out, int out_size, void* d_ws, size_t ws_size,
                              hipStream_t stream) {
  const float* x = (const float*)d_in[0];
  const float* mk = (const float*)d_in[1];
  const float* mv = (const float*)d_in[2];
  const float* Wq = (const float*)d_in[3];
  const float* Wk = (const float*)d_in[4];
  const float* Wv = (const float*)d_in[5];
  const float* Wo = (const float*)d_in[6];
  const float* gatep = (const float*)d_in[7];
  float* out = (float*)d_out;

  char* ws = (char*)d_ws;
  unsigned short* xb   = (unsigned short*)(ws);               // 32MB x bf16; reused as ctx bf16
  unsigned short* Qb   = (unsigned short*)(ws + 33554432);    // 32MB Q bf16 (B,H,T,hd)
  unsigned short* WqT  = (unsigned short*)(ws + 67108864);    // 2MB
  unsigned short* WkvT = (unsigned short*)(ws + 69206016);    // 4MB (Wk^T then Wv^T)
  unsigned short* WoT  = (unsigned short*)(ws + 73400320);    // 2MB
  float* qn    = (float*)(ws + 75497472);                     // 32KB
  float* sims  = (float*)(ws + 75530240);                     // 4MB (first 2MB doubles as part)
  float* part  = (float*)(ws + 75530240);                     // 2MB, dead after k_qnorm
  int*   idx   = (int*)(ws + 79724544);                       // 1KB
  float* cval  = (float*)(ws + 79725568);                     // 64KB
  int*   cidxb = (int*)(ws + 79791104);                       // 64KB
  float* Kws   = (float*)(ws + 79856640);                     // 1MB (B,H,k,hd)
  float* Vws   = (float*)(ws + 80905216);                     // 1MB

  // 1. x -> bf16, fused with mean partial sums
  k_conv_mean<<<dim3(64, 8), 256, 0, stream>>>(x, xb, part);
  // 2. weight transposes -> bf16 B^T layouts
  k_transW<<<dim3(16, 16, 4), 256, 0, stream>>>(Wq, Wk, Wv, Wo,
                                                WqT, WkvT, WkvT + 1048576, WoT);
  // 3. finish mean + normalize
  k_qnorm<<<dim3(8), 256, 0, stream>>>(part, qn);
  // 4. cosine sims vs key bank
  k_sims<<<dim3(BANK / 16), 256, 0, stream>>>(mk, qn, sims);
  // 5. two-stage exact top-32 per batch
  k_topk_local<<<dim3(64, 8), 256, 0, stream>>>(sims, cval, cidxb);
  k_topk_merge<<<dim3(8), 256, 0, stream>>>(cval, cidxb, idx);
  // 6. K,V = mv[idx] @ [Wk;Wv]  (gather fused)
  k_kvgemm<<<dim3(2, 16), 256, 0, stream>>>(mv, idx, WkvT, Kws, Vws);
  // 7. Q = x @ Wq  (writes (B,H,T,hd) bf16)
  k_gemm<0><<<dim3(128, 8), 256, 0, stream>>>(xb, WqT, nullptr, Qb, nullptr, nullptr);
  // 8. attention -> ctx bf16 (reuses xb)
  k_attn<<<dim3(8, 128), 256, 0, stream>>>(Qb, Kws, Vws, xb);
  // 9. out = x + sigmoid(gate) * ctx @ Wo
  k_gemm<2><<<dim3(128, 8), 256, 0, stream>>>(xb, WoT, out, nullptr, x, gatep);
}

// Round 4
// 466.405 us; speedup vs baseline: 1.0834x; 1.0834x over previous
//
#include <hip/hip_runtime.h>

#define D_MODEL 1024
#define NH 16
#define HD 64
#define KRET 32
#define BANK 131072
#define BB 8
#define TT 2048
#define MTOK 16384
#define EPSN 1e-12f

typedef __attribute__((ext_vector_type(8))) short bf16x8;
typedef __attribute__((ext_vector_type(8))) unsigned short u16x8;
typedef __attribute__((ext_vector_type(4))) float f32x4;

__device__ __forceinline__ unsigned short f2bf(float f) {
  unsigned int u = __float_as_uint(f);
  u += 0x7fffu + ((u >> 16) & 1u);
  return (unsigned short)(u >> 16);
}
__device__ __forceinline__ float bf2f(unsigned short h) {
  return __uint_as_float(((unsigned int)h) << 16);
}

__device__ __forceinline__ void gload16(const void* g, void* l) {
  __builtin_amdgcn_global_load_lds(
      (const __attribute__((address_space(1))) unsigned int*)g,
      (__attribute__((address_space(3))) unsigned int*)l, 16, 0, 0);
}

// ---------------- fused: x -> bf16 AND per-(b,chunk32) partial sums ----------------
__global__ __launch_bounds__(256) void k_conv_mean(const float* __restrict__ x,
                                                   unsigned short* __restrict__ xb,
                                                   float* __restrict__ part) {
  int ch = blockIdx.x, b = blockIdx.y, tid = threadIdx.x;
  const float4* xp = (const float4*)(x + ((size_t)b * TT + ch * 32) * D_MODEL);
  ushort4* xo = (ushort4*)(xb + ((size_t)b * TT + ch * 32) * D_MODEL);
  float4 acc = {0.f, 0.f, 0.f, 0.f};
#pragma unroll 4
  for (int t = 0; t < 32; t++) {
    float4 v = xp[t * 256 + tid];
    acc.x += v.x; acc.y += v.y; acc.z += v.z; acc.w += v.w;
    ushort4 o;
    o.x = f2bf(v.x); o.y = f2bf(v.y); o.z = f2bf(v.z); o.w = f2bf(v.w);
    xo[t * 256 + tid] = o;
  }
  ((float4*)part)[((size_t)b * 64 + ch) * 256 + tid] = acc;
}

// ---------------- weight transpose + bf16: WT[n][k] = bf16(W[k][n]) ----------------
__global__ __launch_bounds__(256) void k_transW(const float* W0, const float* W1,
                                                const float* W2, const float* W3,
                                                unsigned short* T0, unsigned short* T1,
                                                unsigned short* T2, unsigned short* T3) {
  const float* W; unsigned short* T;
  switch (blockIdx.z) {
    case 0: W = W0; T = T0; break;
    case 1: W = W1; T = T1; break;
    case 2: W = W2; T = T2; break;
    default: W = W3; T = T3; break;
  }
  __shared__ float tile[64][65];
  int k0 = blockIdx.y * 64, n0 = blockIdx.x * 64;
  int tid = threadIdx.x;
#pragma unroll
  for (int i = 0; i < 16; i++) {
    int idx = tid + i * 256; int r = idx >> 6, c = idx & 63;
    tile[r][c] = W[(size_t)(k0 + r) * D_MODEL + n0 + c];
  }
  __syncthreads();
#pragma unroll
  for (int i = 0; i < 16; i++) {
    int idx = tid + i * 256; int r = idx >> 6, c = idx & 63;
    T[(size_t)(n0 + r) * D_MODEL + k0 + c] = f2bf(tile[c][r]);
  }
}

// ---------------- finish mean (64 partials) + normalize q ----------------
__global__ __launch_bounds__(256) void k_qnorm(const float* __restrict__ part,
                                               float* __restrict__ qn) {
  int b = blockIdx.x; int tid = threadIdx.x;
  __shared__ float red[4];
  const float4* pp = (const float4*)part + (size_t)b * 64 * 256 + tid;
  float4 a = {0.f, 0.f, 0.f, 0.f};
#pragma unroll 8
  for (int p = 0; p < 64; p++) {
    float4 v = pp[(size_t)p * 256];
    a.x += v.x; a.y += v.y; a.z += v.z; a.w += v.w;
  }
  const float sc = 1.f / (float)TT;
  a.x *= sc; a.y *= sc; a.z *= sc; a.w *= sc;
  float ss = a.x * a.x + a.y * a.y + a.z * a.z + a.w * a.w;
#pragma unroll
  for (int m = 32; m >= 1; m >>= 1) ss += __shfl_xor(ss, m);
  if ((tid & 63) == 0) red[tid >> 6] = ss;
  __syncthreads();
  float tot = red[0] + red[1] + red[2] + red[3];
  float inv = 1.f / fmaxf(sqrtf(tot), EPSN);
  float4 o = {a.x * inv, a.y * inv, a.z * inv, a.w * inv};
  ((float4*)qn)[(size_t)b * 256 + tid] = o;
}

// ---------------- cosine sims: one wave per 4 key rows ----------------
__global__ __launch_bounds__(256) void k_sims(const float* __restrict__ mk,
                                              const float* __restrict__ qn,
                                              float* __restrict__ sims) {
  int wave = threadIdx.x >> 6, lane = threadIdx.x & 63;
  int row0 = (blockIdx.x * 4 + wave) * 4;
  float4 kv[4][4];
#pragma unroll
  for (int r = 0; r < 4; r++) {
    const float4* kr = (const float4*)(mk + (size_t)(row0 + r) * D_MODEL);
#pragma unroll
    for (int i = 0; i < 4; i++) kv[r][i] = kr[lane + 64 * i];
  }
  float ss[4] = {0.f, 0.f, 0.f, 0.f};
#pragma unroll
  for (int r = 0; r < 4; r++)
#pragma unroll
    for (int i = 0; i < 4; i++)
      ss[r] += kv[r][i].x * kv[r][i].x + kv[r][i].y * kv[r][i].y +
               kv[r][i].z * kv[r][i].z + kv[r][i].w * kv[r][i].w;
  float dots[8][4];
#pragma unroll
  for (int b = 0; b < 8; b++)
#pragma unroll
    for (int r = 0; r < 4; r++) dots[b][r] = 0.f;
#pragma unroll
  for (int b = 0; b < 8; b++) {
    const float4* qb = (const float4*)(qn + (size_t)b * D_MODEL);
#pragma unroll
    for (int i = 0; i < 4; i++) {
      float4 q4 = qb[lane + 64 * i];
#pragma unroll
      for (int r = 0; r < 4; r++)
        dots[b][r] += kv[r][i].x * q4.x + kv[r][i].y * q4.y +
                      kv[r][i].z * q4.z + kv[r][i].w * q4.w;
    }
  }
#pragma unroll
  for (int m = 32; m >= 1; m >>= 1) {
#pragma unroll
    for (int r = 0; r < 4; r++) ss[r] += __shfl_xor(ss[r], m);
#pragma unroll
    for (int b = 0; b < 8; b++)
#pragma unroll
      for (int r = 0; r < 4; r++) dots[b][r] += __shfl_xor(dots[b][r], m);
  }
  if (lane == 0) {
#pragma unroll
    for (int r = 0; r < 4; r++) {
      float inv = 1.f / fmaxf(sqrtf(ss[r]), EPSN);
#pragma unroll
      for (int b = 0; b < 8; b++)
        sims[(size_t)b * BANK + row0 + r] = dots[b][r] * inv;
    }
  }
}

// ---------------- two-stage exact top-32 ----------------
__global__ __launch_bounds__(256) void k_topk_local(const float* __restrict__ sims,
                                                    float* __restrict__ cval,
                                                    int* __restrict__ cidx) {
  int b = blockIdx.y, chunk = blockIdx.x;
  int tid = threadIdx.x, wave = tid >> 6, lane = tid & 63;
  const float* sb = sims + (size_t)b * BANK + chunk * 2048;
  float v[8]; int gi[8];
#pragma unroll
  for (int j = 0; j < 8; j++) {
    int loc = j * 256 + tid;
    v[j] = sb[loc];
    gi[j] = chunk * 2048 + loc;
  }
  __shared__ float wv[4]; __shared__ int wi[4];
  __shared__ int bcast;
  for (int it = 0; it < KRET; ++it) {
    float best = -1e30f; int besti = 1 << 30;
#pragma unroll
    for (int j = 0; j < 8; j++)
      if (v[j] > best || (v[j] == best && gi[j] < besti)) { best = v[j]; besti = gi[j]; }
#pragma unroll
    for (int m = 32; m >= 1; m >>= 1) {
      float ov = __shfl_xor(best, m); int oi = __shfl_xor(besti, m);
      if (ov > best || (ov == best && oi < besti)) { best = ov; besti = oi; }
    }
    if (lane == 0) { wv[wave] = best; wi[wave] = besti; }
    __syncthreads();
    if (tid == 0) {
      float fb = wv[0]; int fi = wi[0];
      for (int w = 1; w < 4; w++)
        if (wv[w] > fb || (wv[w] == fb && wi[w] < fi)) { fb = wv[w]; fi = wi[w]; }
      bcast = fi;
      cval[((size_t)b * 64 + chunk) * KRET + it] = fb;
      cidx[((size_t)b * 64 + chunk) * KRET + it] = fi;
    }
    __syncthreads();
    int w = bcast;
#pragma unroll
    for (int j = 0; j < 8; j++)
      if (gi[j] == w) v[j] = -1e30f;
  }
}

__global__ __launch_bounds__(256) void k_topk_merge(const float* __restrict__ cval,
                                                    const int* __restrict__ cidx,
                                                    int* __restrict__ idx) {
  int b = blockIdx.x;
  int tid = threadIdx.x, wave = tid >> 6, lane = tid & 63;
  const float* cv = cval + (size_t)b * 2048;
  const int* ci = cidx + (size_t)b * 2048;
  float v[8]; int gi[8];
#pragma unroll
  for (int j = 0; j < 8; j++) {
    int loc = j * 256 + tid;
    v[j] = cv[loc];
    gi[j] = ci[loc];
  }
  __shared__ float wv[4]; __shared__ int wi[4];
  __shared__ int bcast;
  for (int it = 0; it < KRET; ++it) {
    float best = -1e30f; int besti = 1 << 30;
#pragma unroll
    for (int j = 0; j < 8; j++)
      if (v[j] > best || (v[j] == best && gi[j] < besti)) { best = v[j]; besti = gi[j]; }
#pragma unroll
    for (int m = 32; m >= 1; m >>= 1) {
      float ov = __shfl_xor(best, m); int oi = __shfl_xor(besti, m);
      if (ov > best || (ov == best && oi < besti)) { best = ov; besti = oi; }
    }
    if (lane == 0) { wv[wave] = best; wi[wave] = besti; }
    __syncthreads();
    if (tid == 0) {
      float fb = wv[0]; int fi = wi[0];
      for (int w = 1; w < 4; w++)
        if (wv[w] > fb || (wv[w] == fb && wi[w] < fi)) { fb = wv[w]; fi = wi[w]; }
      bcast = fi;
      idx[b * KRET + it] = fi;
    }
    __syncthreads();
    int w = bcast;
#pragma unroll
    for (int j = 0; j < 8; j++)
      if (gi[j] == w) v[j] = -1e30f;
  }
}

// ---------------- KV projection with fused gather: A rows = mv[idx[.]] ----------------
__global__ __launch_bounds__(256) void k_kvgemm(const float* __restrict__ mv,
                                                const int* __restrict__ idx_g,
                                                const unsigned short* __restrict__ Bt,
                                                float* __restrict__ Kout,
                                                float* __restrict__ Vout) {
  __shared__ __align__(16) unsigned short As[128 * 32];
  __shared__ __align__(16) unsigned short Bs[128 * 32];
  __shared__ int idxs[128];
  const int tid = threadIdx.x;
  const int wave = tid >> 6, lane = tid & 63;
  const int bm = blockIdx.x * 128, bn = blockIdx.y * 128;
  const int wm = (wave >> 1) * 64, wn = (wave & 1) * 64;
  const int frow = lane & 15, kg = lane >> 4;
  const int K = 1024;

  if (tid < 128) idxs[tid] = idx_g[bm + tid];
  __syncthreads();

  f32x4 acc[4][4] = {};

  const int row0 = tid >> 2, col0 = (tid & 3) * 8;
  const int row1 = row0 + 64;
  const int g0 = tid * 8;
  const int g1 = 2048 + tid * 8;
  const unsigned short* b0 = Bt + (size_t)(bn + (g0 >> 5)) * K + (g0 & 31);
  const unsigned short* b1 = Bt + (size_t)(bn + (g1 >> 5)) * K + (g1 & 31);
  unsigned short* lB0 = &Bs[wave * 512];
  unsigned short* lB1 = &Bs[2048 + wave * 512];
  const float* src0 = mv + (size_t)idxs[row0] * D_MODEL + col0;
  const float* src1 = mv + (size_t)idxs[row1] * D_MODEL + col0;

  for (int k0 = 0; k0 < K; k0 += 32) {
    gload16(b0 + k0, lB0);
    gload16(b1 + k0, lB1);
    float4 u0 = *(const float4*)(src0 + k0);
    float4 w0 = *(const float4*)(src0 + k0 + 4);
    float4 u1 = *(const float4*)(src1 + k0);
    float4 w1 = *(const float4*)(src1 + k0 + 4);
    u16x8 p0, p1;
    p0[0] = f2bf(u0.x); p0[1] = f2bf(u0.y); p0[2] = f2bf(u0.z); p0[3] = f2bf(u0.w);
    p0[4] = f2bf(w0.x); p0[5] = f2bf(w0.y); p0[6] = f2bf(w0.z); p0[7] = f2bf(w0.w);
    p1[0] = f2bf(u1.x); p1[1] = f2bf(u1.y); p1[2] = f2bf(u1.z); p1[3] = f2bf(u1.w);
    p1[4] = f2bf(w1.x); p1[5] = f2bf(w1.y); p1[6] = f2bf(w1.z); p1[7] = f2bf(w1.w);
    *(u16x8*)&As[row0 * 32 + col0] = p0;
    *(u16x8*)&As[row1 * 32 + col0] = p1;
    __syncthreads();
    bf16x8 fa[4], fb[4];
#pragma unroll
    for (int i = 0; i < 4; i++)
      fa[i] = *(const bf16x8*)&As[(wm + i * 16 + frow) * 32 + kg * 8];
#pragma unroll
    for (int i = 0; i < 4; i++)
      fb[i] = *(const bf16x8*)&Bs[(wn + i * 16 + frow) * 32 + kg * 8];
#pragma unroll
    for (int i = 0; i < 4; i++)
#pragma unroll
      for (int j = 0; j < 4; j++)
        acc[i][j] = __builtin_amdgcn_mfma_f32_16x16x32_bf16(fa[i], fb[j], acc[i][j], 0, 0, 0);
    __syncthreads();
  }

  const int crow = (lane >> 4) * 4, ccol = lane & 15;
#pragma unroll
  for (int i = 0; i < 4; i++)
#pragma unroll
    for (int j = 0; j < 4; j++)
#pragma unroll
      for (int r = 0; r < 4; r++) {
        int gm = bm + wm + i * 16 + crow + r;
        int gn = bn + wn + j * 16 + ccol;
        int b = gm >> 5, jj = gm & 31;
        if (gn < 1024) {
          int h = gn >> 6, d = gn & 63;
          Kout[((((size_t)b * NH + h) * KRET + jj) << 6) + d] = acc[i][j][r];
        } else {
          int gn2 = gn - 1024;
          int h = gn2 >> 6, d = gn2 & 63;
          Vout[((((size_t)b * NH + h) * KRET + jj) << 6) + d] = acc[i][j][r];
        }
      }
}

// ---------------- bf16 MFMA GEMM, 128x128 tile, BK=32 (m97 structure) ----------------
template <int MODE>
__global__ __launch_bounds__(256) void k_gemm(const unsigned short* __restrict__ A,
                                              const unsigned short* __restrict__ Bt,
                                              float* __restrict__ out_f,
                                              unsigned short* __restrict__ out_b,
                                              const float* __restrict__ xres,
                                              const float* __restrict__ gatep) {
  __shared__ __align__(16) unsigned short As[128 * 32];
  __shared__ __align__(16) unsigned short Bs[128 * 32];
  const int tid = threadIdx.x;
  const int wave = tid >> 6, lane = tid & 63;
  const int bm = blockIdx.x * 128, bn = blockIdx.y * 128;
  const int wm = (wave >> 1) * 64, wn = (wave & 1) * 64;
  const int frow = lane & 15, kg = lane >> 4;
  const int K = 1024;

  f32x4 acc[4][4] = {};

  const int g0 = tid * 8;
  const int g1 = 2048 + tid * 8;
  const unsigned short* a0 = A + (size_t)(bm + (g0 >> 5)) * K + (g0 & 31);
  const unsigned short* a1 = A + (size_t)(bm + (g1 >> 5)) * K + (g1 & 31);
  const unsigned short* b0 = Bt + (size_t)(bn + (g0 >> 5)) * K + (g0 & 31);
  const unsigned short* b1 = Bt + (size_t)(bn + (g1 >> 5)) * K + (g1 & 31);
  unsigned short* lA0 = &As[wave * 512];
  unsigned short* lA1 = &As[2048 + wave * 512];
  unsigned short* lB0 = &Bs[wave * 512];
  unsigned short* lB1 = &Bs[2048 + wave * 512];

  for (int k0 = 0; k0 < K; k0 += 32) {
    gload16(a0 + k0, lA0);
    gload16(a1 + k0, lA1);
    gload16(b0 + k0, lB0);
    gload16(b1 + k0, lB1);
    __syncthreads();
    bf16x8 fa[4], fb[4];
#pragma unroll
    for (int i = 0; i < 4; i++)
      fa[i] = *(const bf16x8*)&As[(wm + i * 16 + frow) * 32 + kg * 8];
#pragma unroll
    for (int i = 0; i < 4; i++)
      fb[i] = *(const bf16x8*)&Bs[(wn + i * 16 + frow) * 32 + kg * 8];
#pragma unroll
    for (int i = 0; i < 4; i++)
#pragma unroll
      for (int j = 0; j < 4; j++)
        acc[i][j] = __builtin_amdgcn_mfma_f32_16x16x32_bf16(fa[i], fb[j], acc[i][j], 0, 0, 0);
    __syncthreads();
  }

  const int crow = (lane >> 4) * 4, ccol = lane & 15;
  if (MODE == 2) {
    float gate = 1.f / (1.f + __expf(-gatep[0]));
#pragma unroll
    for (int i = 0; i < 4; i++)
#pragma unroll
      for (int j = 0; j < 4; j++)
#pragma unroll
        for (int r = 0; r < 4; r++) {
          int gm = bm + wm + i * 16 + crow + r;
          int gn = bn + wn + j * 16 + ccol;
          size_t off = (size_t)gm * D_MODEL + gn;
          out_f[off] = xres[off] + gate * acc[i][j][r];
        }
  } else {
#pragma unroll
    for (int i = 0; i < 4; i++)
#pragma unroll
      for (int j = 0; j < 4; j++)
#pragma unroll
        for (int r = 0; r < 4; r++) {
          int gm = bm + wm + i * 16 + crow + r;
          int gn = bn + wn + j * 16 + ccol;
          int b = gm >> 11, t = gm & 2047, h = gn >> 6, d = gn & 63;
          out_b[((((size_t)b * NH + h) * TT + t) << 6) + d] = f2bf(acc[i][j][r]);
        }
  }
}

// ---------------- MFMA cross-attention over k=32 retrieved docs ----------------
// Block: one (b,h), 256 t-rows. Wave w owns 4 independent 16-row subtiles.
// S = Q@K^T (2 doc-tiles x 2 d-steps), in-reg softmax, P via per-wave LDS, PV.
__global__ __launch_bounds__(256) void k_attn(const unsigned short* __restrict__ Qb,
                                              const float* __restrict__ Kws,
                                              const float* __restrict__ Vws,
                                              unsigned short* __restrict__ ctx) {
  __shared__ __align__(16) unsigned short Kl[32 * 72];   // K[doc][d], pad 72
  __shared__ __align__(16) unsigned short Vt[64 * 40];   // V^T[d][doc], pad 40
  __shared__ __align__(16) unsigned short Pl[4][16 * 40];// per-wave P[t][doc], pad 40
  const int bh = blockIdx.y, b = bh >> 4, h = bh & 15;
  const int tid = threadIdx.x, wave = tid >> 6, lane = tid & 63;
  const int t0b = blockIdx.x * 256;
  // stage K (bf16) and V^T (bf16)
  {
    int doc = tid >> 3, d0 = (tid & 7) * 8;
    const float4* kp = (const float4*)(Kws + ((size_t)bh * KRET + doc) * HD + d0);
    float4 k0 = kp[0], k1 = kp[1];
    u16x8 kb;
    kb[0] = f2bf(k0.x); kb[1] = f2bf(k0.y); kb[2] = f2bf(k0.z); kb[3] = f2bf(k0.w);
    kb[4] = f2bf(k1.x); kb[5] = f2bf(k1.y); kb[6] = f2bf(k1.z); kb[7] = f2bf(k1.w);
    *(u16x8*)&Kl[doc * 72 + d0] = kb;
    const float4* vp = (const float4*)(Vws + ((size_t)bh * KRET + doc) * HD + d0);
    float4 v0 = vp[0], v1 = vp[1];
    float vv[8] = {v0.x, v0.y, v0.z, v0.w, v1.x, v1.y, v1.z, v1.w};
#pragma unroll
    for (int j = 0; j < 8; j++) Vt[(d0 + j) * 40 + doc] = f2bf(vv[j]);
  }
  __syncthreads();

  const int fr = lane & 15, kg = lane >> 4;
  // K B-frags (reused across subtiles)
  const bf16x8 kb00 = *(const bf16x8*)&Kl[fr * 72 + kg * 8];
  const bf16x8 kb01 = *(const bf16x8*)&Kl[fr * 72 + 32 + kg * 8];
  const bf16x8 kb10 = *(const bf16x8*)&Kl[(16 + fr) * 72 + kg * 8];
  const bf16x8 kb11 = *(const bf16x8*)&Kl[(16 + fr) * 72 + 32 + kg * 8];
  // V B-frags (reused across subtiles)
  bf16x8 vbf[4];
#pragma unroll
  for (int dt = 0; dt < 4; dt++)
    vbf[dt] = *(const bf16x8*)&Vt[(dt * 16 + fr) * 40 + kg * 8];
  unsigned short* pw = &Pl[wave][0];

#pragma unroll
  for (int sub = 0; sub < 4; ++sub) {
    const int t0 = t0b + wave * 64 + sub * 16;
    const unsigned short* qrow = Qb + ((size_t)bh * TT + t0 + fr) * HD + kg * 8;
    bf16x8 qa0 = *(const bf16x8*)(qrow);
    bf16x8 qa1 = *(const bf16x8*)(qrow + 32);
    f32x4 s0 = {}, s1 = {};
    s0 = __builtin_amdgcn_mfma_f32_16x16x32_bf16(qa0, kb00, s0, 0, 0, 0);
    s0 = __builtin_amdgcn_mfma_f32_16x16x32_bf16(qa1, kb01, s0, 0, 0, 0);
    s1 = __builtin_amdgcn_mfma_f32_16x16x32_bf16(qa0, kb10, s1, 0, 0, 0);
    s1 = __builtin_amdgcn_mfma_f32_16x16x32_bf16(qa1, kb11, s1, 0, 0, 0);
    // softmax over 32 docs; row t = (lane>>4)*4+r lives in 16 lanes (col dim)
    float a0[4], a1[4], mr[4], e0[4], e1[4], sr[4];
#pragma unroll
    for (int r = 0; r < 4; r++) {
      a0[r] = s0[r] * 0.125f; a1[r] = s1[r] * 0.125f;
      mr[r] = fmaxf(a0[r], a1[r]);
    }
#pragma unroll
    for (int m = 1; m < 16; m <<= 1)
#pragma unroll
      for (int r = 0; r < 4; r++) mr[r] = fmaxf(mr[r], __shfl_xor(mr[r], m));
#pragma unroll
    for (int r = 0; r < 4; r++) {
      e0[r] = __expf(a0[r] - mr[r]); e1[r] = __expf(a1[r] - mr[r]);
      sr[r] = e0[r] + e1[r];
    }
#pragma unroll
    for (int m = 1; m < 16; m <<= 1)
#pragma unroll
      for (int r = 0; r < 4; r++) sr[r] += __shfl_xor(sr[r], m);
#pragma unroll
    for (int r = 0; r < 4; r++) {
      float inv = 1.f / sr[r];
      int tl = (lane >> 4) * 4 + r;
      pw[tl * 40 + fr] = f2bf(e0[r] * inv);
      pw[tl * 40 + 16 + fr] = f2bf(e1[r] * inv);
    }
    asm volatile("s_waitcnt lgkmcnt(0)" ::: "memory");
    bf16x8 pa = *(const bf16x8*)&pw[fr * 40 + kg * 8];
    f32x4 c[4];
#pragma unroll
    for (int dt = 0; dt < 4; dt++) {
      f32x4 z = {};
      c[dt] = __builtin_amdgcn_mfma_f32_16x16x32_bf16(pa, vbf[dt], z, 0, 0, 0);
    }
#pragma unroll
    for (int r = 0; r < 4; r++) {
      int tl = (lane >> 4) * 4 + r;
      unsigned short* crow = ctx + ((size_t)(b * TT + t0 + tl)) * D_MODEL + h * HD;
#pragma unroll
      for (int dt = 0; dt < 4; dt++)
        crow[dt * 16 + fr] = f2bf(c[dt][r]);
    }
  }
}

extern "C" void kernel_launch(void* const* d_in, const int* in_sizes, int n_in,
                              void* d_out, int out_size, void* d_ws, size_t ws_size,
                              hipStream_t stream) {
  const float* x = (const float*)d_in[0];
  const float* mk = (const float*)d_in[1];
  const float* mv = (const float*)d_in[2];
  const float* Wq = (const float*)d_in[3];
  const float* Wk = (const float*)d_in[4];
  const float* Wv = (const float*)d_in[5];
  const float* Wo = (const float*)d_in[6];
  const float* gatep = (const float*)d_in[7];
  float* out = (float*)d_out;

  char* ws = (char*)d_ws;
  unsigned short* xb   = (unsigned short*)(ws);               // 32MB x bf16; reused as ctx bf16
  unsigned short* Qb   = (unsigned short*)(ws + 33554432);    // 32MB Q bf16 (B,H,T,hd)
  unsigned short* WqT  = (unsigned short*)(ws + 67108864);    // 2MB
  unsigned short* WkvT = (unsigned short*)(ws + 69206016);    // 4MB (Wk^T then Wv^T)
  unsigned short* WoT  = (unsigned short*)(ws + 73400320);    // 2MB
  float* qn    = (float*)(ws + 75497472);                     // 32KB
  float* sims  = (float*)(ws + 75530240);                     // 4MB (first 2MB doubles as part)
  float* part  = (float*)(ws + 75530240);                     // 2MB, dead after k_qnorm
  int*   idx   = (int*)(ws + 79724544);                       // 1KB
  float* cval  = (float*)(ws + 79725568);                     // 64KB
  int*   cidxb = (int*)(ws + 79791104);                       // 64KB
  float* Kws   = (float*)(ws + 79856640);                     // 1MB (B,H,k,hd)
  float* Vws   = (float*)(ws + 80905216);                     // 1MB

  // 1. x -> bf16, fused with mean partial sums
  k_conv_mean<<<dim3(64, 8), 256, 0, stream>>>(x, xb, part);
  // 2. weight transposes -> bf16 B^T layouts
  k_transW<<<dim3(16, 16, 4), 256, 0, stream>>>(Wq, Wk, Wv, Wo,
                                                WqT, WkvT, WkvT + 1048576, WoT);
  // 3. finish mean + normalize
  k_qnorm<<<dim3(8), 256, 0, stream>>>(part, qn);
  // 4. cosine sims vs key bank
  k_sims<<<dim3(BANK / 16), 256, 0, stream>>>(mk, qn, sims);
  // 5. two-stage exact top-32 per batch
  k_topk_local<<<dim3(64, 8), 256, 0, stream>>>(sims, cval, cidxb);
  k_topk_merge<<<dim3(8), 256, 0, stream>>>(cval, cidxb, idx);
  // 6. K,V = mv[idx] @ [Wk;Wv]  (gather fused)
  k_kvgemm<<<dim3(2, 16), 256, 0, stream>>>(mv, idx, WkvT, Kws, Vws);
  // 7. Q = x @ Wq  (writes (B,H,T,hd) bf16)
  k_gemm<0><<<dim3(128, 8), 256, 0, stream>>>(xb, WqT, nullptr, Qb, nullptr, nullptr);
  // 8. MFMA attention -> ctx bf16 (reuses xb)
  k_attn<<<dim3(8, 128), 256, 0, stream>>>(Qb, Kws, Vws, xb);
  // 9. out = x + sigmoid(gate) * ctx @ Wo
  k_gemm<2><<<dim3(128, 8), 256, 0, stream>>>(xb, WoT, out, nullptr, x, gatep);
}

// Round 5
// 423.590 us; speedup vs baseline: 1.1929x; 1.1011x over previous
//
#include <hip/hip_runtime.h>

#define D_MODEL 1024
#define NH 16
#define HD 64
#define KRET 32
#define BANK 131072
#define BB 8
#define TT 2048
#define MTOK 16384
#define EPSN 1e-12f

typedef __attribute__((ext_vector_type(8))) short bf16x8;
typedef __attribute__((ext_vector_type(8))) unsigned short u16x8;
typedef __attribute__((ext_vector_type(4))) float f32x4;

__device__ __forceinline__ unsigned short f2bf(float f) {
  unsigned int u = __float_as_uint(f);
  u += 0x7fffu + ((u >> 16) & 1u);
  return (unsigned short)(u >> 16);
}
__device__ __forceinline__ float bf2f(unsigned short h) {
  return __uint_as_float(((unsigned int)h) << 16);
}

__device__ __forceinline__ void gload16(const void* g, void* l) {
  __builtin_amdgcn_global_load_lds(
      (const __attribute__((address_space(1))) unsigned int*)g,
      (__attribute__((address_space(3))) unsigned int*)l, 16, 0, 0);
}

// ---------------- fused: x -> bf16 AND per-(b,chunk32) partial sums ----------------
__global__ __launch_bounds__(256) void k_conv_mean(const float* __restrict__ x,
                                                   unsigned short* __restrict__ xb,
                                                   float* __restrict__ part) {
  int ch = blockIdx.x, b = blockIdx.y, tid = threadIdx.x;
  const float4* xp = (const float4*)(x + ((size_t)b * TT + ch * 32) * D_MODEL);
  ushort4* xo = (ushort4*)(xb + ((size_t)b * TT + ch * 32) * D_MODEL);
  float4 acc = {0.f, 0.f, 0.f, 0.f};
#pragma unroll 4
  for (int t = 0; t < 32; t++) {
    float4 v = xp[t * 256 + tid];
    acc.x += v.x; acc.y += v.y; acc.z += v.z; acc.w += v.w;
    ushort4 o;
    o.x = f2bf(v.x); o.y = f2bf(v.y); o.z = f2bf(v.z); o.w = f2bf(v.w);
    xo[t * 256 + tid] = o;
  }
  ((float4*)part)[((size_t)b * 64 + ch) * 256 + tid] = acc;
}

// ---------------- weight transpose + bf16: WT[n][k] = bf16(W[k][n]) ----------------
__global__ __launch_bounds__(256) void k_transW(const float* W0, const float* W1,
                                                const float* W2, const float* W3,
                                                unsigned short* T0, unsigned short* T1,
                                                unsigned short* T2, unsigned short* T3) {
  const float* W; unsigned short* T;
  switch (blockIdx.z) {
    case 0: W = W0; T = T0; break;
    case 1: W = W1; T = T1; break;
    case 2: W = W2; T = T2; break;
    default: W = W3; T = T3; break;
  }
  __shared__ float tile[64][65];
  int k0 = blockIdx.y * 64, n0 = blockIdx.x * 64;
  int tid = threadIdx.x;
#pragma unroll
  for (int i = 0; i < 16; i++) {
    int idx = tid + i * 256; int r = idx >> 6, c = idx & 63;
    tile[r][c] = W[(size_t)(k0 + r) * D_MODEL + n0 + c];
  }
  __syncthreads();
#pragma unroll
  for (int i = 0; i < 16; i++) {
    int idx = tid + i * 256; int r = idx >> 6, c = idx & 63;
    T[(size_t)(n0 + r) * D_MODEL + k0 + c] = f2bf(tile[c][r]);
  }
}

// ---------------- finish mean (64 partials) + normalize q ----------------
__global__ __launch_bounds__(256) void k_qnorm(const float* __restrict__ part,
                                               float* __restrict__ qn) {
  int b = blockIdx.x; int tid = threadIdx.x;
  __shared__ float red[4];
  const float4* pp = (const float4*)part + (size_t)b * 64 * 256 + tid;
  float4 a = {0.f, 0.f, 0.f, 0.f};
#pragma unroll 8
  for (int p = 0; p < 64; p++) {
    float4 v = pp[(size_t)p * 256];
    a.x += v.x; a.y += v.y; a.z += v.z; a.w += v.w;
  }
  const float sc = 1.f / (float)TT;
  a.x *= sc; a.y *= sc; a.z *= sc; a.w *= sc;
  float ss = a.x * a.x + a.y * a.y + a.z * a.z + a.w * a.w;
#pragma unroll
  for (int m = 32; m >= 1; m >>= 1) ss += __shfl_xor(ss, m);
  if ((tid & 63) == 0) red[tid >> 6] = ss;
  __syncthreads();
  float tot = red[0] + red[1] + red[2] + red[3];
  float inv = 1.f / fmaxf(sqrtf(tot), EPSN);
  float4 o = {a.x * inv, a.y * inv, a.z * inv, a.w * inv};
  ((float4*)qn)[(size_t)b * 256 + tid] = o;
}

// ---------------- cosine sims: one wave per 4 key rows ----------------
__global__ __launch_bounds__(256) void k_sims(const float* __restrict__ mk,
                                              const float* __restrict__ qn,
                                              float* __restrict__ sims) {
  int wave = threadIdx.x >> 6, lane = threadIdx.x & 63;
  int row0 = (blockIdx.x * 4 + wave) * 4;
  float4 kv[4][4];
#pragma unroll
  for (int r = 0; r < 4; r++) {
    const float4* kr = (const float4*)(mk + (size_t)(row0 + r) * D_MODEL);
#pragma unroll
    for (int i = 0; i < 4; i++) kv[r][i] = kr[lane + 64 * i];
  }
  float ss[4] = {0.f, 0.f, 0.f, 0.f};
#pragma unroll
  for (int r = 0; r < 4; r++)
#pragma unroll
    for (int i = 0; i < 4; i++)
      ss[r] += kv[r][i].x * kv[r][i].x + kv[r][i].y * kv[r][i].y +
               kv[r][i].z * kv[r][i].z + kv[r][i].w * kv[r][i].w;
  float dots[8][4];
#pragma unroll
  for (int b = 0; b < 8; b++)
#pragma unroll
    for (int r = 0; r < 4; r++) dots[b][r] = 0.f;
#pragma unroll
  for (int b = 0; b < 8; b++) {
    const float4* qb = (const float4*)(qn + (size_t)b * D_MODEL);
#pragma unroll
    for (int i = 0; i < 4; i++) {
      float4 q4 = qb[lane + 64 * i];
#pragma unroll
      for (int r = 0; r < 4; r++)
        dots[b][r] += kv[r][i].x * q4.x + kv[r][i].y * q4.y +
                      kv[r][i].z * q4.z + kv[r][i].w * q4.w;
    }
  }
#pragma unroll
  for (int m = 32; m >= 1; m >>= 1) {
#pragma unroll
    for (int r = 0; r < 4; r++) ss[r] += __shfl_xor(ss[r], m);
#pragma unroll
    for (int b = 0; b < 8; b++)
#pragma unroll
      for (int r = 0; r < 4; r++) dots[b][r] += __shfl_xor(dots[b][r], m);
  }
  if (lane == 0) {
#pragma unroll
    for (int r = 0; r < 4; r++) {
      float inv = 1.f / fmaxf(sqrtf(ss[r]), EPSN);
#pragma unroll
      for (int b = 0; b < 8; b++)
        sims[(size_t)b * BANK + row0 + r] = dots[b][r] * inv;
    }
  }
}

// ---------------- two-stage exact top-32 ----------------
__global__ __launch_bounds__(256) void k_topk_local(const float* __restrict__ sims,
                                                    float* __restrict__ cval,
                                                    int* __restrict__ cidx) {
  int b = blockIdx.y, chunk = blockIdx.x;
  int tid = threadIdx.x, wave = tid >> 6, lane = tid & 63;
  const float* sb = sims + (size_t)b * BANK + chunk * 2048;
  float v[8]; int gi[8];
#pragma unroll
  for (int j = 0; j < 8; j++) {
    int loc = j * 256 + tid;
    v[j] = sb[loc];
    gi[j] = chunk * 2048 + loc;
  }
  __shared__ float wv[4]; __shared__ int wi[4];
  __shared__ int bcast;
  for (int it = 0; it < KRET; ++it) {
    float best = -1e30f; int besti = 1 << 30;
#pragma unroll
    for (int j = 0; j < 8; j++)
      if (v[j] > best || (v[j] == best && gi[j] < besti)) { best = v[j]; besti = gi[j]; }
#pragma unroll
    for (int m = 32; m >= 1; m >>= 1) {
      float ov = __shfl_xor(best, m); int oi = __shfl_xor(besti, m);
      if (ov > best || (ov == best && oi < besti)) { best = ov; besti = oi; }
    }
    if (lane == 0) { wv[wave] = best; wi[wave] = besti; }
    __syncthreads();
    if (tid == 0) {
      float fb = wv[0]; int fi = wi[0];
      for (int w = 1; w < 4; w++)
        if (wv[w] > fb || (wv[w] == fb && wi[w] < fi)) { fb = wv[w]; fi = wi[w]; }
      bcast = fi;
      cval[((size_t)b * 64 + chunk) * KRET + it] = fb;
      cidx[((size_t)b * 64 + chunk) * KRET + it] = fi;
    }
    __syncthreads();
    int w = bcast;
#pragma unroll
    for (int j = 0; j < 8; j++)
      if (gi[j] == w) v[j] = -1e30f;
  }
}

__global__ __launch_bounds__(256) void k_topk_merge(const float* __restrict__ cval,
                                                    const int* __restrict__ cidx,
                                                    int* __restrict__ idx) {
  int b = blockIdx.x;
  int tid = threadIdx.x, wave = tid >> 6, lane = tid & 63;
  const float* cv = cval + (size_t)b * 2048;
  const int* ci = cidx + (size_t)b * 2048;
  float v[8]; int gi[8];
#pragma unroll
  for (int j = 0; j < 8; j++) {
    int loc = j * 256 + tid;
    v[j] = cv[loc];
    gi[j] = ci[loc];
  }
  __shared__ float wv[4]; __shared__ int wi[4];
  __shared__ int bcast;
  for (int it = 0; it < KRET; ++it) {
    float best = -1e30f; int besti = 1 << 30;
#pragma unroll
    for (int j = 0; j < 8; j++)
      if (v[j] > best || (v[j] == best && gi[j] < besti)) { best = v[j]; besti = gi[j]; }
#pragma unroll
    for (int m = 32; m >= 1; m >>= 1) {
      float ov = __shfl_xor(best, m); int oi = __shfl_xor(besti, m);
      if (ov > best || (ov == best && oi < besti)) { best = ov; besti = oi; }
    }
    if (lane == 0) { wv[wave] = best; wi[wave] = besti; }
    __syncthreads();
    if (tid == 0) {
      float fb = wv[0]; int fi = wi[0];
      for (int w = 1; w < 4; w++)
        if (wv[w] > fb || (wv[w] == fb && wi[w] < fi)) { fb = wv[w]; fi = wi[w]; }
      bcast = fi;
      idx[b * KRET + it] = fi;
    }
    __syncthreads();
    int w = bcast;
#pragma unroll
    for (int j = 0; j < 8; j++)
      if (gi[j] == w) v[j] = -1e30f;
  }
}

// ---------------- KV projection with fused gather: A rows = mv[idx[.]] ----------------
__global__ __launch_bounds__(256) void k_kvgemm(const float* __restrict__ mv,
                                                const int* __restrict__ idx_g,
                                                const unsigned short* __restrict__ Bt,
                                                float* __restrict__ Kout,
                                                float* __restrict__ Vout) {
  __shared__ __align__(16) unsigned short As[128 * 32];
  __shared__ __align__(16) unsigned short Bs[128 * 32];
  __shared__ int idxs[128];
  const int tid = threadIdx.x;
  const int wave = tid >> 6, lane = tid & 63;
  const int bm = blockIdx.x * 128, bn = blockIdx.y * 128;
  const int wm = (wave >> 1) * 64, wn = (wave & 1) * 64;
  const int frow = lane & 15, kg = lane >> 4;
  const int K = 1024;

  if (tid < 128) idxs[tid] = idx_g[bm + tid];
  __syncthreads();

  f32x4 acc[4][4] = {};

  const int row0 = tid >> 2, col0 = (tid & 3) * 8;
  const int row1 = row0 + 64;
  const int g0 = tid * 8;
  const int g1 = 2048 + tid * 8;
  const unsigned short* b0 = Bt + (size_t)(bn + (g0 >> 5)) * K + (g0 & 31);
  const unsigned short* b1 = Bt + (size_t)(bn + (g1 >> 5)) * K + (g1 & 31);
  unsigned short* lB0 = &Bs[wave * 512];
  unsigned short* lB1 = &Bs[2048 + wave * 512];
  const float* src0 = mv + (size_t)idxs[row0] * D_MODEL + col0;
  const float* src1 = mv + (size_t)idxs[row1] * D_MODEL + col0;

  for (int k0 = 0; k0 < K; k0 += 32) {
    gload16(b0 + k0, lB0);
    gload16(b1 + k0, lB1);
    float4 u0 = *(const float4*)(src0 + k0);
    float4 w0 = *(const float4*)(src0 + k0 + 4);
    float4 u1 = *(const float4*)(src1 + k0);
    float4 w1 = *(const float4*)(src1 + k0 + 4);
    u16x8 p0, p1;
    p0[0] = f2bf(u0.x); p0[1] = f2bf(u0.y); p0[2] = f2bf(u0.z); p0[3] = f2bf(u0.w);
    p0[4] = f2bf(w0.x); p0[5] = f2bf(w0.y); p0[6] = f2bf(w0.z); p0[7] = f2bf(w0.w);
    p1[0] = f2bf(u1.x); p1[1] = f2bf(u1.y); p1[2] = f2bf(u1.z); p1[3] = f2bf(u1.w);
    p1[4] = f2bf(w1.x); p1[5] = f2bf(w1.y); p1[6] = f2bf(w1.z); p1[7] = f2bf(w1.w);
    *(u16x8*)&As[row0 * 32 + col0] = p0;
    *(u16x8*)&As[row1 * 32 + col0] = p1;
    __syncthreads();
    bf16x8 fa[4], fb[4];
#pragma unroll
    for (int i = 0; i < 4; i++)
      fa[i] = *(const bf16x8*)&As[(wm + i * 16 + frow) * 32 + kg * 8];
#pragma unroll
    for (int i = 0; i < 4; i++)
      fb[i] = *(const bf16x8*)&Bs[(wn + i * 16 + frow) * 32 + kg * 8];
#pragma unroll
    for (int i = 0; i < 4; i++)
#pragma unroll
      for (int j = 0; j < 4; j++)
        acc[i][j] = __builtin_amdgcn_mfma_f32_16x16x32_bf16(fa[i], fb[j], acc[i][j], 0, 0, 0);
    __syncthreads();
  }

  const int crow = (lane >> 4) * 4, ccol = lane & 15;
#pragma unroll
  for (int i = 0; i < 4; i++)
#pragma unroll
    for (int j = 0; j < 4; j++)
#pragma unroll
      for (int r = 0; r < 4; r++) {
        int gm = bm + wm + i * 16 + crow + r;
        int gn = bn + wn + j * 16 + ccol;
        int b = gm >> 5, jj = gm & 31;
        if (gn < 1024) {
          int h = gn >> 6, d = gn & 63;
          Kout[((((size_t)b * NH + h) * KRET + jj) << 6) + d] = acc[i][j][r];
        } else {
          int gn2 = gn - 1024;
          int h = gn2 >> 6, d = gn2 & 63;
          Vout[((((size_t)b * NH + h) * KRET + jj) << 6) + d] = acc[i][j][r];
        }
      }
}

// ---------------- 256x256 8-phase deep-pipelined bf16 GEMM (T2+T3+T4+T5) ----------------
// C(MxN) = A(Mx1024) @ Bt(Nx1024)^T. 512 thr (8 waves 2x4), BK=32, 4-deep LDS ring.
// MODE 0: -> out_b bf16 (B,H,T,hd).  MODE 2: out_f = xres + gate * acc.
#define STG_A(SB, T)                                          \
  do {                                                        \
    const int st_ = (T) < 31 ? (T) : 31;                      \
    gload16(aS0 + st_ * 32, &ldsA[SB][ldst0]);                \
    gload16(aS1 + st_ * 32, &ldsA[SB][ldst1]);                \
  } while (0)
#define STG_B(SB, T)                                          \
  do {                                                        \
    const int st_ = (T) < 31 ? (T) : 31;                      \
    gload16(bS0 + st_ * 32, &ldsB[SB][ldst0]);                \
    gload16(bS1 + st_ * 32, &ldsB[SB][ldst1]);                \
  } while (0)
#define GPH(CB, I0, NEWB, STMT, VM)                                            \
  do {                                                                         \
    bf16x8 af[4];                                                              \
    _Pragma("unroll") for (int ii = 0; ii < 4; ii++)                           \
        af[ii] = *(const bf16x8*)&ldsA[CB][((wr * 128 + (I0 + ii) * 16 + fr) << 5) + (sA << 3)]; \
    if (NEWB) {                                                                \
      _Pragma("unroll") for (int jj = 0; jj < 4; jj++)                         \
          bf[jj] = *(const bf16x8*)&ldsB[CB][((wc * 64 + jj * 16 + fr) << 5) + (sA << 3)]; \
    }                                                                          \
    STMT;                                                                      \
    __builtin_amdgcn_s_barrier();                                              \
    __builtin_amdgcn_s_setprio(1);                                             \
    _Pragma("unroll") for (int ii = 0; ii < 4; ii++)                           \
        _Pragma("unroll") for (int jj = 0; jj < 4; jj++)                       \
            acc[I0 + ii][jj] = __builtin_amdgcn_mfma_f32_16x16x32_bf16(        \
                af[ii], bf[jj], acc[I0 + ii][jj], 0, 0, 0);                    \
    __builtin_amdgcn_s_setprio(0);                                             \
    if (VM) asm volatile("s_waitcnt vmcnt(4)" ::: "memory");                   \
    __builtin_amdgcn_s_barrier();                                              \
  } while (0)

template <int MODE>
__global__ __launch_bounds__(512, 2) void k_gemm8(const unsigned short* __restrict__ A,
                                                  const unsigned short* __restrict__ Bt,
                                                  float* __restrict__ out_f,
                                                  unsigned short* __restrict__ out_b,
                                                  const float* __restrict__ xres,
                                                  const float* __restrict__ gatep) {
  __shared__ __align__(16) unsigned short ldsA[4][8192];
  __shared__ __align__(16) unsigned short ldsB[4][8192];
  const int tid = threadIdx.x;
  const int wid = tid >> 6, lane = tid & 63;
  const int wr = wid >> 2, wc = wid & 3;
  const int fr = lane & 15, kg = lane >> 4;
  const int bm = blockIdx.x * 256, bn = blockIdx.y * 256;
  const int K = 1024;

  f32x4 acc[8][4] = {};
  bf16x8 bf[4];

  // staging: chunk c = q*512+tid -> LDS row c>>2, slot c&3 (16B units).
  // content swizzle (involution): LDS[row][s] = global[row][s ^ ((row>>1)&3)]
  const int r0 = tid >> 2, s0 = tid & 3;
  const int sw0 = s0 ^ ((r0 >> 1) & 3);
  const int r1 = r0 + 128;
  const int sw1 = s0 ^ ((r1 >> 1) & 3);
  const unsigned short* aS0 = A + (size_t)(bm + r0) * K + sw0 * 8;
  const unsigned short* aS1 = A + (size_t)(bm + r1) * K + sw1 * 8;
  const unsigned short* bS0 = Bt + (size_t)(bn + r0) * K + sw0 * 8;
  const unsigned short* bS1 = Bt + (size_t)(bn + r1) * K + sw1 * 8;
  const int ldst0 = wid << 9;            // (wid*64)*8 shorts
  const int ldst1 = 4096 + (wid << 9);   // (512+wid*64)*8
  const int sA = kg ^ ((fr >> 1) & 3);   // read-side swizzled slot

  // prologue: stage tiles 0,1,2 ; wait until tiles 0,1 landed
  STG_A(0, 0); STG_B(0, 0);
  STG_A(1, 1); STG_B(1, 1);
  STG_A(2, 2); STG_B(2, 2);
  asm volatile("s_waitcnt vmcnt(4)" ::: "memory");
  __builtin_amdgcn_s_barrier();

#pragma unroll 1
  for (int it = 0; it < 8; ++it) {
    const int t = it * 4;
    GPH(0, 0, 1, STG_A(3, t + 3), 0);
    GPH(0, 4, 0, STG_B(3, t + 3), 0);
    GPH(1, 0, 1, STG_A(0, t + 4), 0);
    GPH(1, 4, 0, STG_B(0, t + 4), 1);
    GPH(2, 0, 1, STG_A(1, t + 5), 0);
    GPH(2, 4, 0, STG_B(1, t + 5), 0);
    GPH(3, 0, 1, STG_A(2, t + 6), 0);
    GPH(3, 4, 0, STG_B(2, t + 6), 1);
  }

  const int crow = (lane >> 4) * 4, ccol = lane & 15;
  if (MODE == 2) {
    float gate = 1.f / (1.f + __expf(-gatep[0]));
#pragma unroll
    for (int i = 0; i < 8; i++)
#pragma unroll
      for (int j = 0; j < 4; j++)
#pragma unroll
        for (int r = 0; r < 4; r++) {
          int gm = bm + wr * 128 + i * 16 + crow + r;
          int gn = bn + wc * 64 + j * 16 + ccol;
          size_t off = (size_t)gm * D_MODEL + gn;
          out_f[off] = xres[off] + gate * acc[i][j][r];
        }
  } else {
#pragma unroll
    for (int i = 0; i < 8; i++)
#pragma unroll
      for (int j = 0; j < 4; j++)
#pragma unroll
        for (int r = 0; r < 4; r++) {
          int gm = bm + wr * 128 + i * 16 + crow + r;
          int gn = bn + wc * 64 + j * 16 + ccol;
          int b = gm >> 11, tt = gm & 2047, h = gn >> 6, d = gn & 63;
          out_b[((((size_t)b * NH + h) * TT + tt) << 6) + d] = f2bf(acc[i][j][r]);
        }
  }
}

// ---------------- MFMA cross-attention over k=32 retrieved docs ----------------
__global__ __launch_bounds__(256) void k_attn(const unsigned short* __restrict__ Qb,
                                              const float* __restrict__ Kws,
                                              const float* __restrict__ Vws,
                                              unsigned short* __restrict__ ctx) {
  __shared__ __align__(16) unsigned short Kl[32 * 72];   // K[doc][d], pad 72
  __shared__ __align__(16) unsigned short Vt[64 * 40];   // V^T[d][doc], pad 40
  __shared__ __align__(16) unsigned short Pl[4][16 * 40];// per-wave P[t][doc], pad 40
  const int bh = blockIdx.y, b = bh >> 4, h = bh & 15;
  const int tid = threadIdx.x, wave = tid >> 6, lane = tid & 63;
  const int t0b = blockIdx.x * 256;
  {
    int doc = tid >> 3, d0 = (tid & 7) * 8;
    const float4* kp = (const float4*)(Kws + ((size_t)bh * KRET + doc) * HD + d0);
    float4 k0 = kp[0], k1 = kp[1];
    u16x8 kb;
    kb[0] = f2bf(k0.x); kb[1] = f2bf(k0.y); kb[2] = f2bf(k0.z); kb[3] = f2bf(k0.w);
    kb[4] = f2bf(k1.x); kb[5] = f2bf(k1.y); kb[6] = f2bf(k1.z); kb[7] = f2bf(k1.w);
    *(u16x8*)&Kl[doc * 72 + d0] = kb;
    const float4* vp = (const float4*)(Vws + ((size_t)bh * KRET + doc) * HD + d0);
    float4 v0 = vp[0], v1 = vp[1];
    float vv[8] = {v0.x, v0.y, v0.z, v0.w, v1.x, v1.y, v1.z, v1.w};
#pragma unroll
    for (int j = 0; j < 8; j++) Vt[(d0 + j) * 40 + doc] = f2bf(vv[j]);
  }
  __syncthreads();

  const int fr = lane & 15, kg = lane >> 4;
  const bf16x8 kb00 = *(const bf16x8*)&Kl[fr * 72 + kg * 8];
  const bf16x8 kb01 = *(const bf16x8*)&Kl[fr * 72 + 32 + kg * 8];
  const bf16x8 kb10 = *(const bf16x8*)&Kl[(16 + fr) * 72 + kg * 8];
  const bf16x8 kb11 = *(const bf16x8*)&Kl[(16 + fr) * 72 + 32 + kg * 8];
  bf16x8 vbf[4];
#pragma unroll
  for (int dt = 0; dt < 4; dt++)
    vbf[dt] = *(const bf16x8*)&Vt[(dt * 16 + fr) * 40 + kg * 8];
  unsigned short* pw = &Pl[wave][0];

#pragma unroll
  for (int sub = 0; sub < 4; ++sub) {
    const int t0 = t0b + wave * 64 + sub * 16;
    const unsigned short* qrow = Qb + ((size_t)bh * TT + t0 + fr) * HD + kg * 8;
    bf16x8 qa0 = *(const bf16x8*)(qrow);
    bf16x8 qa1 = *(const bf16x8*)(qrow + 32);
    f32x4 s0 = {}, s1 = {};
    s0 = __builtin_amdgcn_mfma_f32_16x16x32_bf16(qa0, kb00, s0, 0, 0, 0);
    s0 = __builtin_amdgcn_mfma_f32_16x16x32_bf16(qa1, kb01, s0, 0, 0, 0);
    s1 = __builtin_amdgcn_mfma_f32_16x16x32_bf16(qa0, kb10, s1, 0, 0, 0);
    s1 = __builtin_amdgcn_mfma_f32_16x16x32_bf16(qa1, kb11, s1, 0, 0, 0);
    float a0[4], a1[4], mr[4], e0[4], e1[4], sr[4];
#pragma unroll
    for (int r = 0; r < 4; r++) {
      a0[r] = s0[r] * 0.125f; a1[r] = s1[r] * 0.125f;
      mr[r] = fmaxf(a0[r], a1[r]);
    }
#pragma unroll
    for (int m = 1; m < 16; m <<= 1)
#pragma unroll
      for (int r = 0; r < 4; r++) mr[r] = fmaxf(mr[r], __shfl_xor(mr[r], m));
#pragma unroll
    for (int r = 0; r < 4; r++) {
      e0[r] = __expf(a0[r] - mr[r]); e1[r] = __expf(a1[r] - mr[r]);
      sr[r] = e0[r] + e1[r];
    }
#pragma unroll
    for (int m = 1; m < 16; m <<= 1)
#pragma unroll
      for (int r = 0; r < 4; r++) sr[r] += __shfl_xor(sr[r], m);
#pragma unroll
    for (int r = 0; r < 4; r++) {
      float inv = 1.f / sr[r];
      int tl = (lane >> 4) * 4 + r;
      pw[tl * 40 + fr] = f2bf(e0[r] * inv);
      pw[tl * 40 + 16 + fr] = f2bf(e1[r] * inv);
    }
    asm volatile("s_waitcnt lgkmcnt(0)" ::: "memory");
    bf16x8 pa = *(const bf16x8*)&pw[fr * 40 + kg * 8];
    f32x4 c[4];
#pragma unroll
    for (int dt = 0; dt < 4; dt++) {
      f32x4 z = {};
      c[dt] = __builtin_amdgcn_mfma_f32_16x16x32_bf16(pa, vbf[dt], z, 0, 0, 0);
    }
#pragma unroll
    for (int r = 0; r < 4; r++) {
      int tl = (lane >> 4) * 4 + r;
      unsigned short* crow = ctx + ((size_t)(b * TT + t0 + tl)) * D_MODEL + h * HD;
#pragma unroll
      for (int dt = 0; dt < 4; dt++)
        crow[dt * 16 + fr] = f2bf(c[dt][r]);
    }
  }
}

extern "C" void kernel_launch(void* const* d_in, const int* in_sizes, int n_in,
                              void* d_out, int out_size, void* d_ws, size_t ws_size,
                              hipStream_t stream) {
  const float* x = (const float*)d_in[0];
  const float* mk = (const float*)d_in[1];
  const float* mv = (const float*)d_in[2];
  const float* Wq = (const float*)d_in[3];
  const float* Wk = (const float*)d_in[4];
  const float* Wv = (const float*)d_in[5];
  const float* Wo = (const float*)d_in[6];
  const float* gatep = (const float*)d_in[7];
  float* out = (float*)d_out;

  char* ws = (char*)d_ws;
  unsigned short* xb   = (unsigned short*)(ws);               // 32MB x bf16; reused as ctx bf16
  unsigned short* Qb   = (unsigned short*)(ws + 33554432);    // 32MB Q bf16 (B,H,T,hd)
  unsigned short* WqT  = (unsigned short*)(ws + 67108864);    // 2MB
  unsigned short* WkvT = (unsigned short*)(ws + 69206016);    // 4MB (Wk^T then Wv^T)
  unsigned short* WoT  = (unsigned short*)(ws + 73400320);    // 2MB
  float* qn    = (float*)(ws + 75497472);                     // 32KB
  float* sims  = (float*)(ws + 75530240);                     // 4MB (first 2MB doubles as part)
  float* part  = (float*)(ws + 75530240);                     // 2MB, dead after k_qnorm
  int*   idx   = (int*)(ws + 79724544);                       // 1KB
  float* cval  = (float*)(ws + 79725568);                     // 64KB
  int*   cidxb = (int*)(ws + 79791104);                       // 64KB
  float* Kws   = (float*)(ws + 79856640);                     // 1MB (B,H,k,hd)
  float* Vws   = (float*)(ws + 80905216);                     // 1MB

  // 1. x -> bf16, fused with mean partial sums
  k_conv_mean<<<dim3(64, 8), 256, 0, stream>>>(x, xb, part);
  // 2. weight transposes -> bf16 B^T layouts
  k_transW<<<dim3(16, 16, 4), 256, 0, stream>>>(Wq, Wk, Wv, Wo,
                                                WqT, WkvT, WkvT + 1048576, WoT);
  // 3. finish mean + normalize
  k_qnorm<<<dim3(8), 256, 0, stream>>>(part, qn);
  // 4. cosine sims vs key bank
  k_sims<<<dim3(BANK / 16), 256, 0, stream>>>(mk, qn, sims);
  // 5. two-stage exact top-32 per batch
  k_topk_local<<<dim3(64, 8), 256, 0, stream>>>(sims, cval, cidxb);
  k_topk_merge<<<dim3(8), 256, 0, stream>>>(cval, cidxb, idx);
  // 6. K,V = mv[idx] @ [Wk;Wv]  (gather fused)
  k_kvgemm<<<dim3(2, 16), 256, 0, stream>>>(mv, idx, WkvT, Kws, Vws);
  // 7. Q = x @ Wq  (8-phase 256^2, writes (B,H,T,hd) bf16)
  k_gemm8<0><<<dim3(64, 4), 512, 0, stream>>>(xb, WqT, nullptr, Qb, nullptr, nullptr);
  // 8. MFMA attention -> ctx bf16 (reuses xb)
  k_attn<<<dim3(8, 128), 256, 0, stream>>>(Qb, Kws, Vws, xb);
  // 9. out = x + sigmoid(gate) * ctx @ Wo  (8-phase 256^2)
  k_gemm8<2><<<dim3(64, 4), 512, 0, stream>>>(xb, WoT, out, nullptr, x, gatep);
}